// Round 10
// baseline (477.366 us; speedup 1.0000x reference)
//
#include <hip/hip_runtime.h>
#include <math.h>

#define Nn 512
#define Ld 64
#define NB 8
#define C1 32
#define C2 25      // 3*NB+1

// ---- exact math helpers (field-proven r1..r7) ----
// algebraically identical to tanh-gelu: 0.5a(1+tanh(u)) == a/(1+exp(-2u))
__device__ __forceinline__ float gelu_fast(float a) {
    float a3 = a * a * a;
    float u2 = 1.5957691216057308f * (a + 0.044715f * a3);   // 2*0.79788456...
    return a / (1.0f + __expf(-u2));
}

__device__ __forceinline__ float softplus_f(float v) {
    return (v > 0.0f) ? v + log1pf(expf(-v)) : log1pf(expf(v));
}

__device__ __forceinline__ float pos_mod_2pi(float v) {
    const float T = 6.2831853071795864769f;
    float r = fmodf(v, T);
    if (r < 0.0f) r += T;
    return r;
}

// ===== fused conv1+gelu (LDS) -> conv2 -> spline; 16-row bands, 384 threads =====
#define BTH 384        // block threads (6 waves)
#define RB 16          // band rows (64 = 4 x 16, uniform bands)
#define FCH 4          // conv1 channels per chunk (8 chunks)
#define ISTR 67        // input frame stride: 66 cols (global -1..64) + 1 pad
#define IROWS 20       // staged input rows (RB+4)
#define HROWS 18       // h1 rows (RB+2)
#define HPLANE (HROWS * 64)   // 1152: h1 plane per channel (rows r0-1..r0+16, cols 0..63)

// conv1+gelu for one h1 slot S (h=S>>6, j=S&63 -> site row r0-1+h, col j); frame base B
#define H1SLOT(S, B)                                                      \
    {                                                                     \
        float vv[18];                                                     \
        _Pragma("unroll")                                                 \
        for (int di = 0; di < 3; ++di)                                    \
            _Pragma("unroll")                                             \
            for (int dj = 0; dj < 3; ++dj) {                              \
                int a = (B) + di * ISTR + dj;                             \
                vv[di * 3 + dj]     = s_cos[a];                           \
                vv[9 + di * 3 + dj] = s_sin[a];                           \
            }                                                             \
        _Pragma("unroll")                                                 \
        for (int c = 0; c < FCH; ++c) {                                   \
            const float* w = c1w + (c0 + c) * 18;   /* uniform s_load */  \
            float a1 = c1b[c0 + c];                                       \
            _Pragma("unroll")                                             \
            for (int t = 0; t < 9; ++t) {   /* cos/sin interleaved */     \
                a1 = fmaf(vv[t],     w[t],     a1);                       \
                a1 = fmaf(vv[9 + t], w[9 + t], a1);                       \
            }                                                             \
            s_h1[c * HPLANE + (S)] = gelu_fast(a1);                       \
        }                                                                 \
    }

// conv2 accumulate over FCH channels of chunk CBASE (proven pattern, 64-col rows)
#define CONV2(CBASE)                                                      \
    {                                                                     \
        _Pragma("unroll 1")                                               \
        for (int c = 0; c < FCH; ++c) {                                   \
            const int eb = c * HPLANE;                                    \
            float v0 = s_h1[eb + ex0];                                    \
            float v1 = s_h1[eb + ex1];                                    \
            float v2 = s_h1[eb + ex2];                                    \
            float v3 = s_h1[eb + ex0 + 64];                               \
            float v4 = s_h1[eb + ex1 + 64];                               \
            float v5 = s_h1[eb + ex2 + 64];                               \
            float v6 = s_h1[eb + ex0 + 128];                              \
            float v7 = s_h1[eb + ex1 + 128];                              \
            float v8 = s_h1[eb + ex2 + 128];                              \
            const float* wpc = c2w + ((CBASE) + c) * 9;                   \
            _Pragma("unroll")                                             \
            for (int co = 0; co < C2; ++co) {                             \
                const float* w = wpc + co * (C1 * 9);  /* uniform */      \
                float a2 = acc[co];                                       \
                a2 = fmaf(v0, w[0], a2);                                  \
                a2 = fmaf(v1, w[1], a2);                                  \
                a2 = fmaf(v2, w[2], a2);                                  \
                a2 = fmaf(v3, w[3], a2);                                  \
                a2 = fmaf(v4, w[4], a2);                                  \
                a2 = fmaf(v5, w[5], a2);                                  \
                a2 = fmaf(v6, w[6], a2);                                  \
                a2 = fmaf(v7, w[7], a2);                                  \
                a2 = fmaf(v8, w[8], a2);                                  \
                acc[co] = a2;                                             \
            }                                                             \
        }                                                                 \
    }

__global__ __launch_bounds__(BTH, 7) void csplaq_fused_kernel(
    const float* __restrict__ x,
    const float* __restrict__ c1w, const float* __restrict__ c1b,
    const float* __restrict__ c2w, const float* __restrict__ c2b,
    float* __restrict__ out_fx, float* __restrict__ out_logJ)
{
    __shared__ float s_cos[IROWS * ISTR];   // 1340 f = 5360 B
    __shared__ float s_sin[IROWS * ISTR];   // 5360 B
    __shared__ float s_h1[FCH * HPLANE];    // 4608 f = 18432 B
    __shared__ float s_red[6];              // total 29176 B -> 5 blocks/CU

    const float TWO_PI_F = 6.2831853071795864769f;

    const int tid  = threadIdx.x;
    const int band = blockIdx.x;            // 0..3 (uniform 16-row bands)
    const int n    = blockIdx.y;
    const int r0   = band * RB;
    const float* xn = x + n * 4096;

    // ---- stage frozen-masked cos/sin: rows r0-2..r0+17, cols -1..64 (66) ----
    for (int idx = tid; idx < IROWS * 66; idx += BTH) {
        int li = idx / 66, u = idx - li * 66;
        int gi = (r0 - 2 + li) & 63;
        int gj = (u - 1) & 63;
        float xv = xn[gi * 64 + gj];
        int pat = (gi + 2 * gj) % 3;
        float sv, cv;
        sincosf(xv, &sv, &cv);
        float fz = (pat == 2) ? 1.0f : 0.0f;
        s_cos[li * ISTR + u] = fz * cv;
        s_sin[li * ISTR + u] = fz * sv;
    }

    // ---- active-site mapping (generalized 22/21/21 groups; residue rho = r0%3) ----
    // lattice row r: active cols ≡ r (mod 3); count 22 iff r%3==0 else 21.
    // 5 groups of 3 rows = 64 actives each (tids 0..319); tail row 15 (tids 320..).
    const int g3 = tid >> 6, u = tid & 63;
    const int rho = r0 % 3;                      // band%3
    const int k22 = (3 - rho) % 3;               // group-row with 22 actives
    const int n0 = (k22 == 0) ? 22 : 21;
    const int n1 = (k22 == 1) ? 22 : 21;
    const int b1 = n0, b2 = n0 + n1;
    int rr, cc;
    bool is_act;
    if (g3 < 5) {
        int rsel  = (u >= b1) + (u >= b2);
        int ubase = (rsel == 2) ? b2 : ((rsel == 1) ? b1 : 0);
        rr = 3 * g3 + rsel;                      // local band row 0..14
        int cres = rho + rsel; if (cres > 2) cres -= 3;   // (r0+rr)%3
        cc = 3 * (u - ubase) + cres;
        is_act = true;
    } else {
        int m = tid - 320;                       // tail: local row 15
        rr = 15;
        cc = 3 * m + rho;                        // (r0+15)%3 == rho
        is_act = (m < ((rho == 0) ? 22 : 21));
    }
    const int jm = (cc + 63) & 63, jp = (cc + 1) & 63;   // wrapped window cols

    // h1-plane gather offsets: site row r0+rr -> plane rows rr..rr+2
    const int ex0 = rr * 64 + jm, ex1 = rr * 64 + cc, ex2 = rr * 64 + jp;

    // ---- h1 slot decomposition: 1152 slots = 3 x 384 exactly (no guards) ----
    const int sA = tid, sB = tid + BTH, sC = tid + 2 * BTH;
    const int bA = (sA >> 6) * ISTR + (sA & 63);
    const int bB = (sB >> 6) * ISTR + (sB & 63);
    const int bC = (sC >> 6) * ISTR + (sC & 63);

    float acc[C2];
    #pragma unroll
    for (int co = 0; co < C2; ++co) acc[co] = c2b[co];

    // ---- chunk loop: conv1+gelu -> LDS, conv2 accumulate (h1 never in HBM) ----
    #pragma unroll 1
    for (int c0 = 0; c0 < C1; c0 += FCH) {
        __syncthreads();                 // prev chunk consumed (1st iter: staging done)
        H1SLOT(sA, bA)
        H1SLOT(sB, bB)
        H1SLOT(sC, bC)
        __syncthreads();                 // h1 chunk visible
        if (is_act) CONV2(c0)
    }

    // ---- passive/frozen pass-through ----
    float* outn = out_fx + n * 4096;
    for (int idx = tid; idx < RB * 64; idx += BTH) {
        int lr = idx >> 6, c = idx & 63;
        int gi = r0 + lr;
        int pat = (gi + 2 * c) % 3;
        float xv = xn[gi * 64 + c];
        if (pat != 0) outn[gi * 64 + c] = xv;
    }

    // ---- spline at the active site (exact math, proven) ----
    float lj_val = 0.0f;
    if (is_act) {
        int gi = r0 + rr;
        float xv = xn[gi * 64 + cc];

        float kx[NB + 1], ky[NB + 1], sar[NB + 1];
        {
            float m = acc[0];
            #pragma unroll
            for (int qi = 1; qi < NB; ++qi) m = fmaxf(m, acc[qi]);
            float e[NB], ssum = 0.0f;
            #pragma unroll
            for (int qi = 0; qi < NB; ++qi) { e[qi] = expf(acc[qi] - m); ssum += e[qi]; }
            float inv = TWO_PI_F / ssum;
            float run = 0.0f;
            kx[0] = 0.0f;
            #pragma unroll
            for (int qi = 0; qi < NB; ++qi) { run += e[qi]; kx[qi + 1] = run * inv; }
        }
        {
            float m = acc[NB];
            #pragma unroll
            for (int qi = 1; qi < NB; ++qi) m = fmaxf(m, acc[NB + qi]);
            float e[NB], ssum = 0.0f;
            #pragma unroll
            for (int qi = 0; qi < NB; ++qi) { e[qi] = expf(acc[NB + qi] - m); ssum += e[qi]; }
            float inv = TWO_PI_F / ssum;
            float run = 0.0f;
            ky[0] = 0.0f;
            #pragma unroll
            for (int qi = 0; qi < NB; ++qi) { run += e[qi]; ky[qi + 1] = run * inv; }
        }
        #pragma unroll
        for (int qi = 0; qi < NB; ++qi) sar[qi] = softplus_f(acc[2 * NB + qi]);
        sar[NB] = sar[0];
        float t_out = acc[3 * NB];

        float x1 = pos_mod_2pi(xv);
        int k = 0;
        #pragma unroll
        for (int qi = 1; qi <= NB - 1; ++qi) k += (x1 >= kx[qi]) ? 1 : 0;

        float kxk = 0.f, kxk1 = 0.f, kyk = 0.f, kyk1 = 0.f, sk = 0.f, sk1 = 0.f;
        #pragma unroll
        for (int qi = 0; qi <= NB; ++qi) {
            if (qi == k)     { kxk = kx[qi];  kyk = ky[qi];  sk  = sar[qi]; }
            if (qi == k + 1) { kxk1 = kx[qi]; kyk1 = ky[qi]; sk1 = sar[qi]; }
        }

        float wk = kxk1 - kxk;
        float hk = kyk1 - kyk;
        float slope = hk / wk;
        float xi = (x1 - kxk) / wk;
        xi = fminf(fmaxf(xi, 0.0f), 1.0f);
        float om = 1.0f - xi;
        float den = slope + (sk1 + sk - 2.0f * slope) * xi * om;
        float y = kyk + hk * (slope * xi * xi + sk * xi * om) / den;
        float num = slope * slope * (sk1 * xi * xi + 2.0f * slope * xi * om + sk * om * om);
        lj_val = logf(num) - 2.0f * logf(den);

        outn[gi * 64 + cc] = pos_mod_2pi(y + t_out);
    }

    // ---- logJ: wave shuffle -> LDS -> one atomic per block ----
    float r = lj_val;
    #pragma unroll
    for (int off = 32; off > 0; off >>= 1) r += __shfl_down(r, off, 64);
    int lane = tid & 63, wv = tid >> 6;
    if (lane == 0) s_red[wv] = r;
    __syncthreads();
    if (tid == 0)
        atomicAdd(&out_logJ[n], s_red[0] + s_red[1] + s_red[2] +
                                s_red[3] + s_red[4] + s_red[5]);
}

extern "C" void kernel_launch(void* const* d_in, const int* in_sizes, int n_in,
                              void* d_out, int out_size, void* d_ws, size_t ws_size,
                              hipStream_t stream) {
    const float* x   = (const float*)d_in[0];
    // d_in[1..3] masks: recomputed analytically ((i+2j)%3) -> exact
    const float* c1w = (const float*)d_in[4];
    const float* c1b = (const float*)d_in[5];
    const float* c2w = (const float*)d_in[6];
    const float* c2b = (const float*)d_in[7];

    float* out_fx   = (float*)d_out;
    float* out_logJ = out_fx + (size_t)Nn * Ld * Ld;

    hipMemsetAsync(out_logJ, 0, Nn * sizeof(float), stream);

    dim3 grid(4, Nn);
    csplaq_fused_kernel<<<grid, BTH, 0, stream>>>(x, c1w, c1b, c2w, c2b,
                                                  out_fx, out_logJ);
}

// Round 12
// 352.932 us; speedup vs baseline: 1.3526x; 1.3526x over previous
//
#include <hip/hip_runtime.h>
#include <math.h>

#define Nn 512
#define Ld 64
#define NB 8
#define C1 32
#define C2 25      // 3*NB+1

// ---- exact math helpers (field-proven r1..r10) ----
// algebraically identical to tanh-gelu: 0.5a(1+tanh(u)) == a/(1+exp(-2u))
__device__ __forceinline__ float gelu_fast(float a) {
    float a3 = a * a * a;
    float u2 = 1.5957691216057308f * (a + 0.044715f * a3);   // 2*0.79788456...
    return a / (1.0f + __expf(-u2));
}

__device__ __forceinline__ float softplus_f(float v) {
    return (v > 0.0f) ? v + log1pf(expf(-v)) : log1pf(expf(v));
}

__device__ __forceinline__ float pos_mod_2pi(float v) {
    const float T = 6.2831853071795864769f;
    float r = fmodf(v, T);
    if (r < 0.0f) r += T;
    return r;
}

// ===== fused: conv1+gelu (LDS) -> conv2 -> spline; r7 geometry, FCH=4 =====
// Single change vs the measured-387us r7 kernel: FCH 8->4 (LDS 37.4->22.9 KB,
// 4->7 blocks/CU). Barrier count 9->17 -- isolates occupancy-vs-barrier question.
#define FCH 4          // conv1 channels per chunk (8 chunks)
#define ISTR 67        // input frame stride: 66 cols (global -1..64) + 1 pad
#define IROWS 16       // max staged input rows (R+4)
#define HPLANE 896     // h1 plane per channel: 14 rows x 64 cols

// conv1+gelu for one h1 slot S (h=S>>6 -> site row r0-1+h, j=S&63); frame base B
#define H1SLOT(S, B, V)                                                   \
    if (V) {                                                              \
        float vv[18];                                                     \
        _Pragma("unroll")                                                 \
        for (int di = 0; di < 3; ++di)                                    \
            _Pragma("unroll")                                             \
            for (int dj = 0; dj < 3; ++dj) {                              \
                int a = (B) + di * ISTR + dj;                             \
                vv[di * 3 + dj]     = s_cos[a];                           \
                vv[9 + di * 3 + dj] = s_sin[a];                           \
            }                                                             \
        _Pragma("unroll")                                                 \
        for (int c = 0; c < FCH; ++c) {                                   \
            const float* w = c1w + (c0 + c) * 18;   /* uniform s_load */  \
            float a1 = c1b[c0 + c];                                       \
            _Pragma("unroll")                                             \
            for (int t = 0; t < 9; ++t) {   /* cos/sin interleaved */     \
                a1 = fmaf(vv[t],     w[t],     a1);                       \
                a1 = fmaf(vv[9 + t], w[9 + t], a1);                       \
            }                                                             \
            s_h1[c * HPLANE + (S)] = gelu_fast(a1);                       \
        }                                                                 \
    }

// conv2 accumulate over FCH channels of chunk CBASE (proven pattern, 64-col rows)
#define CONV2(CBASE)                                                      \
    {                                                                     \
        _Pragma("unroll 1")                                               \
        for (int c = 0; c < FCH; ++c) {                                   \
            const int eb = c * HPLANE;                                    \
            float v0 = s_h1[eb + ex0];                                    \
            float v1 = s_h1[eb + ex1];                                    \
            float v2 = s_h1[eb + ex2];                                    \
            float v3 = s_h1[eb + ex0 + 64];                               \
            float v4 = s_h1[eb + ex1 + 64];                               \
            float v5 = s_h1[eb + ex2 + 64];                               \
            float v6 = s_h1[eb + ex0 + 128];                              \
            float v7 = s_h1[eb + ex1 + 128];                              \
            float v8 = s_h1[eb + ex2 + 128];                              \
            const float* wpc = c2w + ((CBASE) + c) * 9;                   \
            _Pragma("unroll")                                             \
            for (int co = 0; co < C2; ++co) {                             \
                const float* w = wpc + co * (C1 * 9);  /* uniform */      \
                float a2 = acc[co];                                       \
                a2 = fmaf(v0, w[0], a2);                                  \
                a2 = fmaf(v1, w[1], a2);                                  \
                a2 = fmaf(v2, w[2], a2);                                  \
                a2 = fmaf(v3, w[3], a2);                                  \
                a2 = fmaf(v4, w[4], a2);                                  \
                a2 = fmaf(v5, w[5], a2);                                  \
                a2 = fmaf(v6, w[6], a2);                                  \
                a2 = fmaf(v7, w[7], a2);                                  \
                a2 = fmaf(v8, w[8], a2);                                  \
                acc[co] = a2;                                             \
            }                                                             \
        }                                                                 \
    }

__global__ __launch_bounds__(256, 7) void csplaq_fused_kernel(
    const float* __restrict__ x,
    const float* __restrict__ c1w, const float* __restrict__ c1b,
    const float* __restrict__ c2w, const float* __restrict__ c2b,
    float* __restrict__ out_fx, float* __restrict__ out_logJ)
{
    __shared__ float s_cos[IROWS * ISTR];   // 1072 f = 4288 B
    __shared__ float s_sin[IROWS * ISTR];   // 4288 B
    __shared__ float s_h1[FCH * HPLANE];    // 3584 f = 14336 B
    __shared__ float s_red[4];              // total ~22.9 KB -> 7 blocks/CU

    const float TWO_PI_F = 6.2831853071795864769f;

    const int tid  = threadIdx.x;
    const int band = blockIdx.x;            // 0..5
    const int n    = blockIdx.y;
    const int r0   = band * 12;
    const int R    = (band == 5) ? 4 : 12;
    const int rows_in = R + 4;              // staged input rows (16 or 8)
    const int rows_l  = R + 2;              // h1 rows (14 or 6)
    const int nsh     = rows_l * 64;        // h1 sites (896 or 384)
    const int n_active = (R == 12) ? 256 : 86;
    const float* xn = x + n * 4096;

    // ---- stage frozen-masked cos/sin: rows r0-2..r0+R+1, cols -1..64 (66) ----
    for (int idx = tid; idx < rows_in * 66; idx += 256) {
        int li = idx / 66, u = idx - li * 66;
        int gi = (r0 - 2 + li) & 63;
        int gj = (u - 1) & 63;
        float xv = xn[gi * 64 + gj];
        int pat = (gi + 2 * gj) % 3;
        float sv, cv;
        sincosf(xv, &sv, &cv);
        float fz = (pat == 2) ? 1.0f : 0.0f;
        s_cos[li * ISTR + u] = fz * cv;
        s_sin[li * ISTR + u] = fz * sv;
    }

    // ---- active-site mapping (proven): rows 3g..3g+2 hold 22,21,21 actives ----
    int g3 = tid >> 6, u = tid & 63;
    int rsel  = (u >= 22) + (u >= 43);
    int ubase = (rsel == 2) ? 43 : ((rsel == 1) ? 22 : 0);
    int rr = 3 * g3 + rsel;                 // local band row (site gi = r0+rr)
    int cc = 3 * (u - ubase) + rsel;        // global col
    bool is_act = (tid < n_active);
    int jm = (cc + 63) & 63, jp = (cc + 1) & 63;   // wrapped window cols

    // h1-plane gather offsets: site row gi=r0+rr -> plane rows rr..rr+2
    const int ex0 = rr * 64 + jm, ex1 = rr * 64 + cc, ex2 = rr * 64 + jp;

    // ---- h1 slot decomposition (shift-only, loop-invariant) ----
    const int sA = tid, sB = tid + 256, sC = tid + 512, sD = tid + 768;
    const int bA = (sA >> 6) * ISTR + (sA & 63);
    const int bB = (sB >> 6) * ISTR + (sB & 63);
    const int bC = (sC >> 6) * ISTR + (sC & 63);
    const int bD = (sD >> 6) * ISTR + (sD & 63);
    const bool vA = (sA < nsh), vB = (sB < nsh), vC = (sC < nsh), vD = (sD < nsh);

    float acc[C2];
    #pragma unroll
    for (int co = 0; co < C2; ++co) acc[co] = c2b[co];

    // ---- chunk loop: conv1+gelu -> LDS, then conv2 accumulate (h1 never in HBM) ----
    #pragma unroll 1
    for (int c0 = 0; c0 < C1; c0 += FCH) {
        __syncthreads();                 // prev chunk fully consumed (and staging ready)
        H1SLOT(sA, bA, vA)
        H1SLOT(sB, bB, vB)
        H1SLOT(sC, bC, vC)
        H1SLOT(sD, bD, vD)
        __syncthreads();                 // h1 chunk visible
        if (is_act) CONV2(c0)
    }

    // ---- passive/frozen pass-through ----
    float* outn = out_fx + n * 4096;
    for (int idx = tid; idx < R * 64; idx += 256) {
        int lr = idx >> 6, c = idx & 63;
        int gi = r0 + lr;
        int pat = (gi + 2 * c) % 3;
        float xv = xn[gi * 64 + c];
        if (pat != 0) outn[gi * 64 + c] = xv;
    }

    // ---- spline at the active site (exact math, proven) ----
    float lj_val = 0.0f;
    if (is_act) {
        int gi = r0 + rr;
        float xv = xn[gi * 64 + cc];

        float kx[NB + 1], ky[NB + 1], sar[NB + 1];
        {
            float m = acc[0];
            #pragma unroll
            for (int qi = 1; qi < NB; ++qi) m = fmaxf(m, acc[qi]);
            float e[NB], ssum = 0.0f;
            #pragma unroll
            for (int qi = 0; qi < NB; ++qi) { e[qi] = expf(acc[qi] - m); ssum += e[qi]; }
            float inv = TWO_PI_F / ssum;
            float run = 0.0f;
            kx[0] = 0.0f;
            #pragma unroll
            for (int qi = 0; qi < NB; ++qi) { run += e[qi]; kx[qi + 1] = run * inv; }
        }
        {
            float m = acc[NB];
            #pragma unroll
            for (int qi = 1; qi < NB; ++qi) m = fmaxf(m, acc[NB + qi]);
            float e[NB], ssum = 0.0f;
            #pragma unroll
            for (int qi = 0; qi < NB; ++qi) { e[qi] = expf(acc[NB + qi] - m); ssum += e[qi]; }
            float inv = TWO_PI_F / ssum;
            float run = 0.0f;
            ky[0] = 0.0f;
            #pragma unroll
            for (int qi = 0; qi < NB; ++qi) { run += e[qi]; ky[qi + 1] = run * inv; }
        }
        #pragma unroll
        for (int qi = 0; qi < NB; ++qi) sar[qi] = softplus_f(acc[2 * NB + qi]);
        sar[NB] = sar[0];
        float t_out = acc[3 * NB];

        float x1 = pos_mod_2pi(xv);
        int k = 0;
        #pragma unroll
        for (int qi = 1; qi <= NB - 1; ++qi) k += (x1 >= kx[qi]) ? 1 : 0;

        float kxk = 0.f, kxk1 = 0.f, kyk = 0.f, kyk1 = 0.f, sk = 0.f, sk1 = 0.f;
        #pragma unroll
        for (int qi = 0; qi <= NB; ++qi) {
            if (qi == k)     { kxk = kx[qi];  kyk = ky[qi];  sk  = sar[qi]; }
            if (qi == k + 1) { kxk1 = kx[qi]; kyk1 = ky[qi]; sk1 = sar[qi]; }
        }

        float wk = kxk1 - kxk;
        float hk = kyk1 - kyk;
        float slope = hk / wk;
        float xi = (x1 - kxk) / wk;
        xi = fminf(fmaxf(xi, 0.0f), 1.0f);
        float om = 1.0f - xi;
        float den = slope + (sk1 + sk - 2.0f * slope) * xi * om;
        float y = kyk + hk * (slope * xi * xi + sk * xi * om) / den;
        float num = slope * slope * (sk1 * xi * xi + 2.0f * slope * xi * om + sk * om * om);
        lj_val = logf(num) - 2.0f * logf(den);

        outn[gi * 64 + cc] = pos_mod_2pi(y + t_out);
    }

    // ---- logJ: wave shuffle -> LDS -> one atomic per block ----
    float r = lj_val;
    #pragma unroll
    for (int off = 32; off > 0; off >>= 1) r += __shfl_down(r, off, 64);
    int lane = tid & 63, wv = tid >> 6;
    if (lane == 0) s_red[wv] = r;
    __syncthreads();
    if (tid == 0)
        atomicAdd(&out_logJ[n], s_red[0] + s_red[1] + s_red[2] + s_red[3]);
}

extern "C" void kernel_launch(void* const* d_in, const int* in_sizes, int n_in,
                              void* d_out, int out_size, void* d_ws, size_t ws_size,
                              hipStream_t stream) {
    const float* x   = (const float*)d_in[0];
    // d_in[1..3] masks: recomputed analytically ((i+2j)%3) -> exact
    const float* c1w = (const float*)d_in[4];
    const float* c1b = (const float*)d_in[5];
    const float* c2w = (const float*)d_in[6];
    const float* c2b = (const float*)d_in[7];

    float* out_fx   = (float*)d_out;
    float* out_logJ = out_fx + (size_t)Nn * Ld * Ld;

    hipMemsetAsync(out_logJ, 0, Nn * sizeof(float), stream);

    dim3 grid(6, Nn);
    csplaq_fused_kernel<<<grid, 256, 0, stream>>>(x, c1w, c1b, c2w, c2b,
                                                  out_fx, out_logJ);
}